// Round 20
// baseline (57.380 us; speedup 1.0000x reference)
//
#include <hip/hip_runtime.h>
#include <hip/hip_bf16.h>

// Sizes
#define NB 8
#define NC 4
#define NN 1024
#define ND 96
#define NHH 3
#define DKV 32
#define NBC (NB*NC)        // 32
#define NHEAD (NBC*NHH)    // 96
#define NROWS (NBC*NN)     // 32768
// log2(e) / sqrt(32)  (folded into K at projection time)
#define C1 0.25503486910638953f
#define EPSV 1e-5f

using short8 = __attribute__((ext_vector_type(8))) short;
using sh4    = __attribute__((ext_vector_type(4))) short;
using f32x4  = __attribute__((ext_vector_type(4))) float;
using f32x16 = __attribute__((ext_vector_type(16))) float;

__device__ __forceinline__ short bf16_of(float f) {
  __hip_bfloat16 h = __float2bfloat16(f);
  return __builtin_bit_cast(short, h);
}
__device__ __forceinline__ float f_of_bf16(short s) {
  return __bfloat162float(__builtin_bit_cast(__hip_bfloat16, s));
}

__device__ __forceinline__ short8 load_cvt8(const float* p) {
  float4 f0 = *(const float4*)p;
  float4 f1 = *(const float4*)(p + 4);
  short8 v;
  v[0] = bf16_of(f0.x); v[1] = bf16_of(f0.y); v[2] = bf16_of(f0.z); v[3] = bf16_of(f0.w);
  v[4] = bf16_of(f1.x); v[5] = bf16_of(f1.y); v[6] = bf16_of(f1.z); v[7] = bf16_of(f1.w);
  return v;
}

// async global->LDS, 16B per lane; LDS dest = wave-uniform base + lane*16
__device__ __forceinline__ void gload_lds16(const void* g, void* l) {
  __builtin_amdgcn_global_load_lds(
      (const __attribute__((address_space(1))) unsigned int*)g,
      (__attribute__((address_space(3))) unsigned int*)l,
      16, 0, 0);
}

// ---------------------------------------------------------------------------
// Kernel 1: projections, p split across blocks. W staged with vectorized
// float4 loads + b64 writes; x staged via LDS; output transposed through
// xlds -> coalesced 16B stores. (round-19 body) grid 1536, block 256.
// ---------------------------------------------------------------------------
__global__ __launch_bounds__(256) void proj_kernel(
    const float* __restrict__ xq, const float* __restrict__ xk, const float* __restrict__ xv,
    const float* __restrict__ Wq, const float* __restrict__ Wk, const float* __restrict__ Wv,
    short* __restrict__ qb, short* __restrict__ kb, short* __restrict__ vb)
{
  __shared__ __align__(16) short wlds[96][104];
  __shared__ __align__(16) short xlds[64][104];
  const int t = threadIdx.x;
  const int p = blockIdx.x >> 9;               // 0..2
  const int blkrow0 = (blockIdx.x & 511) * 64;

  const float* x = (p == 0) ? xq : (p == 1) ? xk : xv;
  const float* W = (p == 0) ? Wq : (p == 1) ? Wk : Wv;
  short* dst = (p == 0) ? qb : (p == 1) ? kb : vb;
  const float sc = (p == 1) ? C1 : 1.0f;

#pragma unroll
  for (int i = 0; i < 9; ++i) {
    const int idx = i*256 + t;
    const float4 wv = *(const float4*)(W + (size_t)idx*4);
    const int f = idx*4, row = f/96, col = f%96;
    sh4 w4;
    w4[0] = bf16_of(wv.x); w4[1] = bf16_of(wv.y);
    w4[2] = bf16_of(wv.z); w4[3] = bf16_of(wv.w);
    *(sh4*)&wlds[row][col] = w4;
  }
#pragma unroll
  for (int it = 0; it < 3; ++it) {
    const int f = it*2048 + t*8;               // 96%8==0: no row straddle
    const int row = f / 96, col = f % 96;
    *(short8*)&xlds[row][col] = load_cvt8(x + (size_t)(blkrow0 + row)*ND + col);
  }
  __syncthreads();

  const int wave = t >> 6, lane = t & 63;
  const int g = lane >> 4, li = lane & 15;
  const int acol = g * 8;

  const short8 a0 = *(const short8*)&xlds[wave*16 + li][acol];
  const short8 a1 = *(const short8*)&xlds[wave*16 + li][32 + acol];
  const short8 a2 = *(const short8*)&xlds[wave*16 + li][64 + acol];

  f32x4 oacc[6];
#pragma unroll
  for (int tt = 0; tt < 6; ++tt) {
    f32x4 acc = {0.f, 0.f, 0.f, 0.f};
    const short* wr = &wlds[tt*16 + li][acol];
    acc = __builtin_amdgcn_mfma_f32_16x16x32_bf16(a0, *(const short8*)(wr),      acc, 0, 0, 0);
    acc = __builtin_amdgcn_mfma_f32_16x16x32_bf16(a1, *(const short8*)(wr + 32), acc, 0, 0, 0);
    acc = __builtin_amdgcn_mfma_f32_16x16x32_bf16(a2, *(const short8*)(wr + 64), acc, 0, 0, 0);
    oacc[tt] = acc;
  }

#pragma unroll
  for (int tt = 0; tt < 6; ++tt)
#pragma unroll
    for (int r = 0; r < 4; ++r)
      xlds[wave*16 + g*4 + r][tt*16 + li] = bf16_of(oacc[tt][r] * sc);
  __syncthreads();

#pragma unroll
  for (int it = 0; it < 3; ++it) {
    const int task = it*256 + t;               // 0..767 = 64 rows x 12 short8
    const int nn_l = task / 12, seg = task - nn_l*12;
    const int col8 = seg*8;
    const int h = col8 >> 5, dd = col8 & 31;
    const int n = blkrow0 + nn_l;
    const int bcx = n >> 10, nnx = n & 1023;
    *(short8*)&dst[((size_t)(bcx*NHH + h)*NN + nnx)*DKV + dd] =
        *(const short8*)&xlds[nn_l][col8];
  }
}

// ---------------------------------------------------------------------------
// Kernel 2: column softmax sums + V' transposed. (round-19 body)
// grid 96*8, block 256.
// ---------------------------------------------------------------------------
__global__ __launch_bounds__(256) void stats_kernel(
    const short* __restrict__ qb, const short* __restrict__ kb,
    const short* __restrict__ vb, short* __restrict__ vtb)
{
  __shared__ __align__(16) short s_q[2][4096];   // 2 x 8KB linear
  __shared__ float s_is[128];
  __shared__ __align__(16) short s_t[32][128];   // V' transpose buf (swizzled)

  const int t = threadIdx.x, wave = t >> 6, lane = t & 63;
  const int g = lane >> 4, li = lane & 15;
  const int head = blockIdx.x % NHEAD;           // XCD-aware
  const int kblk = blockIdx.x / NHEAD;           // 0..7
  const int kb0 = kblk*128;
  const int k0 = kb0 + wave*32;

  const short* kr = kb + ((size_t)head*NN + k0)*DKV + g*8;
  const short8 af0 = *(const short8*)(kr + (size_t)li*DKV);
  const short8 af1 = *(const short8*)(kr + (size_t)(16 + li)*DKV);

  const int nl = t >> 1;              // 0..127 (local k)
  const int dvs = (t & 1) * 16;       // dv segment base
  const short* vrow = vb + ((size_t)head*NN + kb0 + nl)*DKV + dvs;
  const short8 v0 = *(const short8*)(vrow);
  const short8 v1 = *(const short8*)(vrow + 8);

  const char* qsrc = (const char*)(qb + (size_t)head*NN*DKV);
  char* sq0 = (char*)&s_q[0][0];
  char* sq1 = (char*)&s_q[1][0];
  const int wseg = wave*2048;

  f32x4 s0 = {0.f,0.f,0.f,0.f}, s1 = {0.f,0.f,0.f,0.f};

#pragma unroll
  for (int j = 0; j < 2; ++j)
    gload_lds16(qsrc + wseg + j*1024 + lane*16, sq0 + wseg + j*1024);
  __syncthreads();

  for (int qc = 0; qc < 8; ++qc) {
    const int cur = qc & 1;
    const short* scur = (const short*)(cur ? sq1 : sq0);
    char* snxt = cur ? sq0 : sq1;
    if (qc < 7) {
#pragma unroll
      for (int j = 0; j < 2; ++j)
        gload_lds16(qsrc + (size_t)(qc+1)*8192 + wseg + j*1024 + lane*16,
                    snxt + wseg + j*1024);
    }
    __builtin_amdgcn_s_setprio(1);
#pragma unroll
    for (int qt = 0; qt < 8; ++qt) {
      const short8 bf = *(const short8*)(scur + (qt*16 + li)*32 + g*8);
      f32x4 z = {0.f,0.f,0.f,0.f};
      f32x4 d0 = __builtin_amdgcn_mfma_f32_16x16x32_bf16(af0, bf, z, 0, 0, 0);
      f32x4 d1 = __builtin_amdgcn_mfma_f32_16x16x32_bf16(af1, bf, z, 0, 0, 0);
#pragma unroll
      for (int r = 0; r < 4; ++r) {
        s0[r] += __builtin_amdgcn_exp2f(d0[r]);
        s1[r] += __builtin_amdgcn_exp2f(d1[r]);
      }
    }
    __builtin_amdgcn_s_setprio(0);
    __syncthreads();   // drains glds (next buf ready) + orders buf reuse
  }

#pragma unroll
  for (int ms = 1; ms <= 8; ms <<= 1) {
#pragma unroll
    for (int r = 0; r < 4; ++r) {
      s0[r] += __shfl_xor(s0[r], ms);
      s1[r] += __shfl_xor(s1[r], ms);
    }
  }
  if (li == 0) {
    float* dst = s_is + wave*32 + g*4;
#pragma unroll
    for (int r = 0; r < 4; ++r) {
      dst[r]      = 1.0f / s0[r];
      dst[16 + r] = 1.0f / s1[r];
    }
  }
  __syncthreads();

  // ---- V' phase A: scale prefetched vb rows by is[n], scatter to transpose
  {
    const float isv = s_is[nl];
    short* st = &s_t[0][0];
#pragma unroll
    for (int j = 0; j < 8; ++j) {
      const int dv0 = dvs + j, dv1 = dvs + 8 + j;
      st[dv0*128 + (((nl*2) ^ ((dv0 & 7) << 4)) >> 1)] = bf16_of(isv * f_of_bf16(v0[j]));
      st[dv1*128 + (((nl*2) ^ ((dv1 & 7) << 4)) >> 1)] = bf16_of(isv * f_of_bf16(v1[j]));
    }
  }
  __syncthreads();

  // ---- V' phase B: coalesced write to vtb [head][dv][n]
  {
    const short* st = &s_t[0][0];
#pragma unroll
    for (int it = 0; it < 2; ++it) {
      const int task = it*256 + t;      // 0..511
      const int dv = task >> 4, ns = task & 15;
      short8 v = *(const short8*)(st + dv*128 + (((ns*16) ^ ((dv & 7) << 4)) >> 1));
      *(short8*)(vtb + ((size_t)head*DKV + dv)*NN + kb0 + ns*8) = v;
    }
  }
}

// ---------------------------------------------------------------------------
// Kernel 3: FUSED context + fc + LN, HEAD-PARALLEL, now 3-DEEP PIPELINED
// (T3/T4): 3 LDS buffers per head slot; per iter issue chunk kc+2, MFMA on
// chunk kc, then counted s_waitcnt vmcnt(4) (waits only chunk kc+1; kc+2's
// loads stay in flight across the barrier) + raw s_barrier. Buffer algebra:
// iter kc writes buf (kc+2)%3 == (kc-1)%3, whose readers finished before the
// iter-(kc-1) barrier (ds_read results consumed by MFMA pre-barrier).
// Entry-time global loads (Wfc regs, Q frags) are force-materialized via
// empty asm so vmcnt counting stays sound. Dynamic LDS 72KB (2 blocks/CU).
// grid 32*16 = 512, block 384.
// ---------------------------------------------------------------------------
__global__ __launch_bounds__(384) void ctxout_kernel(
    const short* __restrict__ qb, const short* __restrict__ kb,
    const short* __restrict__ vtb, const float* __restrict__ resid,
    const float* __restrict__ Wfc, const float* __restrict__ gamma,
    const float* __restrict__ beta, float* __restrict__ out)
{
  extern __shared__ __align__(16) char smem[];   // 73728 B dynamic

  const int t = threadIdx.x;
  const int w = t >> 6, lane = t & 63;
  const int li = lane & 31, hi = lane >> 5;
  const int hs = t >> 7;                 // 0..2 head slot (128 thr each)
  const int sub = w & 1;                 // wave parity within slot
  const int bc = blockIdx.x % NBC;       // XCD-affine (32 % 8 == 0)
  const int qtile = blockIdx.x / NBC;    // 0..15
  const int q0 = qtile*64 + sub*32;
  const int head = bc*NHH + hs;

  // Wfc reg-stage (f32x4 for asm-materialization), coalesced
  f32x4 wreg[6];
#pragma unroll
  for (int i = 0; i < 6; ++i)
    wreg[i] = *(const f32x4*)(Wfc + i*1536 + t*4);

  char* kbase = smem + hs*24576;         // 3 bufs x 4KB K (swizzled rows)
  char* vbase = kbase + 12288;           // 3 bufs x 4KB V'

  const short* kgp = kb  + (size_t)head*NN*DKV;
  const short* vgp = vtb + (size_t)head*DKV*NN;
  const short* qrow = qb + ((size_t)head*NN + q0 + li)*DKV;
  short8 qf0 = *(const short8*)(qrow + hi*8);
  short8 qf1 = *(const short8*)(qrow + 16 + hi*8);

  // force all entry loads complete BEFORE staging issues (sound vmcnt counts)
#pragma unroll
  for (int i = 0; i < 6; ++i) asm volatile("" : "+v"(wreg[i]));
  asm volatile("" : "+v"(qf0), "+v"(qf1));

  // per-lane inverse-swizzled source offsets (bytes) + wave-uniform LDS segs
  int kgoff[2], vgoff[2], ldsseg[2];
#pragma unroll
  for (int j = 0; j < 2; ++j) {
    const int b = (sub*2 + j)*1024 + lane*16;   // LDS byte this lane fills
    const int r = b >> 7, c = b & 127;
    const int pc = c ^ ((r & 7) << 4);
    const int xk6 = r + 32*(pc >> 6);
    const int kr = (xk6 & 51) | ((xk6 & 4) << 1) | ((xk6 & 8) >> 1);  // tau
    kgoff[j] = kr*64 + (pc & 63);               // within 4096B K chunk
    vgoff[j] = r*(NN*2) + pc;                   // V' rows stride NN*2 bytes
    ldsseg[j] = (sub*2 + j)*1024;               // uniform per wave
  }

  int rd_off[2][2];
#pragma unroll
  for (int kt = 0; kt < 2; ++kt) {
    const int base = kt*64 + hi*16;
    rd_off[kt][0] = li*128 + ((base)      ^ ((li & 7) << 4));
    rd_off[kt][1] = li*128 + ((base + 32) ^ ((li & 7) << 4));
  }

  f32x16 acc = {0.f,0.f,0.f,0.f,0.f,0.f,0.f,0.f,0.f,0.f,0.f,0.f,0.f,0.f,0.f,0.f};

  // prologue: chunks 0,1 -> bufs 0,1 (8 issues/thread; 4 per chunk)
#pragma unroll
  for (int c = 0; c < 2; ++c) {
    const size_t kadv = (size_t)c*4096;
    const int vadv = c*128;
#pragma unroll
    for (int j = 0; j < 2; ++j) {
      gload_lds16((const char*)kgp + kadv + kgoff[j], kbase + c*4096 + ldsseg[j]);
      gload_lds16((const char*)vgp + vadv + vgoff[j], vbase + c*4096 + ldsseg[j]);
    }
  }
  __builtin_amdgcn_sched_barrier(0);
  asm volatile("s_waitcnt vmcnt(4)" ::: "memory");   // chunk 0 complete
  __builtin_amdgcn_s_barrier();
  __builtin_amdgcn_sched_barrier(0);

  for (int kc = 0; kc < 16; ++kc) {
    const int cur = kc % 3;
    if (kc < 14) {
      const int nb = (kc + 2) % 3;
      const size_t kadv = (size_t)(kc+2)*4096;
      const int vadv = (kc+2)*128;
#pragma unroll
      for (int j = 0; j < 2; ++j) {
        gload_lds16((const char*)kgp + kadv + kgoff[j], kbase + nb*4096 + ldsseg[j]);
        gload_lds16((const char*)vgp + vadv + vgoff[j], vbase + nb*4096 + ldsseg[j]);
      }
    }
    const char* kc_b = kbase + cur*4096;
    const char* vc_b = vbase + cur*4096;

    __builtin_amdgcn_s_setprio(1);
#pragma unroll
    for (int kt = 0; kt < 2; ++kt) {
      const short8 a0 = *(const short8*)(kc_b + rd_off[kt][0]);
      const short8 a1 = *(const short8*)(kc_b + rd_off[kt][1]);
      f32x16 sT = {0.f,0.f,0.f,0.f,0.f,0.f,0.f,0.f,0.f,0.f,0.f,0.f,0.f,0.f,0.f,0.f};
      sT = __builtin_amdgcn_mfma_f32_32x32x16_bf16(a0, qf0, sT, 0, 0, 0);
      sT = __builtin_amdgcn_mfma_f32_32x32x16_bf16(a1, qf1, sT, 0, 0, 0);
      short8 pa0, pa1;
#pragma unroll
      for (int j = 0; j < 8; ++j) {
        pa0[j] = bf16_of(__builtin_amdgcn_exp2f(sT[j]));
        pa1[j] = bf16_of(__builtin_amdgcn_exp2f(sT[8 + j]));
      }
      const short8 vfa = *(const short8*)(vc_b + rd_off[kt][0]);
      const short8 vfb = *(const short8*)(vc_b + rd_off[kt][1]);
      acc = __builtin_amdgcn_mfma_f32_32x32x16_bf16(pa0, vfa, acc, 0, 0, 0);
      acc = __builtin_amdgcn_mfma_f32_32x32x16_bf16(pa1, vfb, acc, 0, 0, 0);
    }
    __builtin_amdgcn_s_setprio(0);

    __builtin_amdgcn_sched_barrier(0);
    if (kc < 14) asm volatile("s_waitcnt vmcnt(4)" ::: "memory");  // chunk kc+1 done
    else         asm volatile("s_waitcnt vmcnt(0)" ::: "memory");  // tail drain
    __builtin_amdgcn_s_barrier();
    __builtin_amdgcn_sched_barrier(0);
  }

  // ---- epilogue (union reuse safe: all waves past the final barrier) ----
  short* s_ct = (short*)smem;            // [64][104]
  short* wlds = (short*)(smem + 13312);  // [96][104]

#pragma unroll
  for (int reg = 0; reg < 16; ++reg) {
    const int ql = sub*32 + (reg & 3) + 8*(reg >> 2) + 4*hi;
    s_ct[ql*104 + hs*32 + li] = bf16_of(acc[reg]);
  }
  // Wfc: regs -> LDS (f = i*1536 + t*4; 96%4==0 so a float4 never straddles)
#pragma unroll
  for (int i = 0; i < 6; ++i) {
    const int f = i*1536 + t*4;
    const int row = f / 96, col = f % 96;
    sh4 w4;
    w4[0] = bf16_of(wreg[i][0]); w4[1] = bf16_of(wreg[i][1]);
    w4[2] = bf16_of(wreg[i][2]); w4[3] = bf16_of(wreg[i][3]);
    *(sh4*)&wlds[row*104 + col] = w4;
  }
  __syncthreads();

  if (w < 4) {
    const int g16 = lane >> 4, li16 = lane & 15;
    const int rbase = w*16;
    const size_t rowg = (size_t)bc*NN + qtile*64 + rbase;

    const short* ar = s_ct + (rbase + li16)*104 + g16*8;
    const short8 a0 = *(const short8*)(ar);
    const short8 a1 = *(const short8*)(ar + 32);
    const short8 a2 = *(const short8*)(ar + 64);

    float o[6][4];
#pragma unroll
    for (int tt = 0; tt < 6; ++tt) {
      f32x4 oa = {0.f, 0.f, 0.f, 0.f};
      const short* wr = wlds + (tt*16 + li16)*104 + g16*8;
      oa = __builtin_amdgcn_mfma_f32_16x16x32_bf16(a0, *(const short8*)(wr),      oa, 0, 0, 0);
      oa = __builtin_amdgcn_mfma_f32_16x16x32_bf16(a1, *(const short8*)(wr + 32), oa, 0, 0, 0);
      oa = __builtin_amdgcn_mfma_f32_16x16x32_bf16(a2, *(const short8*)(wr + 64), oa, 0, 0, 0);
#pragma unroll
      for (int r = 0; r < 4; ++r)
        o[tt][r] = oa[r] + resid[(rowg + g16*4 + r)*ND + tt*16 + li16];
    }

    float s1v[4], s2v[4];
#pragma unroll
    for (int r = 0; r < 4; ++r) {
      float a = 0.f, b = 0.f;
#pragma unroll
      for (int tt = 0; tt < 6; ++tt) { a += o[tt][r]; b += o[tt][r]*o[tt][r]; }
      s1v[r] = a; s2v[r] = b;
    }
#pragma unroll
    for (int ms = 1; ms <= 8; ms <<= 1) {
#pragma unroll
      for (int r = 0; r < 4; ++r) {
        s1v[r] += __shfl_xor(s1v[r], ms);
        s2v[r] += __shfl_xor(s2v[r], ms);
      }
    }
    float mean[4], rs[4];
#pragma unroll
    for (int r = 0; r < 4; ++r) {
      mean[r] = s1v[r] * (1.0f/96.0f);
      float var = s2v[r]*(1.0f/96.0f) - mean[r]*mean[r];
      rs[r] = rsqrtf(var + EPSV);
    }
#pragma unroll
    for (int tt = 0; tt < 6; ++tt) {
      const int e = tt*16 + li16;
      const float gg = gamma[e], bb = beta[e];
#pragma unroll
      for (int r = 0; r < 4; ++r)
        out[(rowg + g16*4 + r)*ND + e] = (o[tt][r] - mean[r])*rs[r]*gg + bb;
    }
  }
}

// ---------------------------------------------------------------------------
extern "C" void kernel_launch(void* const* d_in, const int* in_sizes, int n_in,
                              void* d_out, int out_size, void* d_ws, size_t ws_size,
                              hipStream_t stream) {
  (void)in_sizes; (void)n_in; (void)out_size; (void)ws_size;
  const float* xq    = (const float*)d_in[0];
  const float* xk    = (const float*)d_in[1];
  const float* xv    = (const float*)d_in[2];
  const float* Wq    = (const float*)d_in[3];
  const float* Wk    = (const float*)d_in[4];
  const float* Wv    = (const float*)d_in[5];
  const float* Wfc   = (const float*)d_in[6];
  const float* gamma = (const float*)d_in[7];
  const float* beta  = (const float*)d_in[8];
  float* out = (float*)d_out;

  // Workspace (18.9 MB: qb + kb + vtb + vb)
  short* qb  = (short*)d_ws;                         // [head][n][32]
  short* kb  = qb  + (size_t)NHEAD*NN*DKV;           // [head][n][32] (x C1)
  short* vtb = kb  + (size_t)NHEAD*NN*DKV;           // [head][32][n] = is[k]*V
  short* vb  = vtb + (size_t)NHEAD*NN*DKV;           // [head][n][32] (dead after stats)

  // allow 72KB dynamic LDS for the 3-deep pipeline (deterministic, host-side)
  hipFuncSetAttribute((const void*)ctxout_kernel,
                      hipFuncAttributeMaxDynamicSharedMemorySize, 73728);

  hipLaunchKernelGGL(proj_kernel,   dim3(3*NROWS/64), dim3(256), 0, stream,
                     xq, xk, xv, Wq, Wk, Wv, qb, kb, vb);
  hipLaunchKernelGGL(stats_kernel,  dim3(NHEAD*8), dim3(256), 0, stream,
                     qb, kb, vb, vtb);
  hipLaunchKernelGGL(ctxout_kernel, dim3(NBC*16), dim3(384), 73728, stream,
                     qb, kb, vtb, xq, Wfc, gamma, beta, out);
}

// Round 21
// 56.444 us; speedup vs baseline: 1.0166x; 1.0166x over previous
//
#include <hip/hip_runtime.h>
#include <hip/hip_bf16.h>

// Sizes
#define NB 8
#define NC 4
#define NN 1024
#define ND 96
#define NHH 3
#define DKV 32
#define NBC (NB*NC)        // 32
#define NHEAD (NBC*NHH)    // 96
#define NROWS (NBC*NN)     // 32768
// log2(e) / sqrt(32)  (folded into K at projection time)
#define C1 0.25503486910638953f
#define EPSV 1e-5f

using short8 = __attribute__((ext_vector_type(8))) short;
using sh4    = __attribute__((ext_vector_type(4))) short;
using f32x4  = __attribute__((ext_vector_type(4))) float;
using f32x16 = __attribute__((ext_vector_type(16))) float;

__device__ __forceinline__ short bf16_of(float f) {
  __hip_bfloat16 h = __float2bfloat16(f);
  return __builtin_bit_cast(short, h);
}
__device__ __forceinline__ float f_of_bf16(short s) {
  return __bfloat162float(__builtin_bit_cast(__hip_bfloat16, s));
}

__device__ __forceinline__ short8 load_cvt8(const float* p) {
  float4 f0 = *(const float4*)p;
  float4 f1 = *(const float4*)(p + 4);
  short8 v;
  v[0] = bf16_of(f0.x); v[1] = bf16_of(f0.y); v[2] = bf16_of(f0.z); v[3] = bf16_of(f0.w);
  v[4] = bf16_of(f1.x); v[5] = bf16_of(f1.y); v[6] = bf16_of(f1.z); v[7] = bf16_of(f1.w);
  return v;
}

// async global->LDS, 16B per lane; LDS dest = wave-uniform base + lane*16
__device__ __forceinline__ void gload_lds16(const void* g, void* l) {
  __builtin_amdgcn_global_load_lds(
      (const __attribute__((address_space(1))) unsigned int*)g,
      (__attribute__((address_space(3))) unsigned int*)l,
      16, 0, 0);
}

// ---------------------------------------------------------------------------
// Kernel 1: projections, p split across blocks. W staged in LDS with
// vectorized float4 loads + b64 writes; x staged via LDS; output transposed
// through xlds -> coalesced 16B stores. grid 1536 = 3 x 512, block 256.
// ---------------------------------------------------------------------------
__global__ __launch_bounds__(256) void proj_kernel(
    const float* __restrict__ xq, const float* __restrict__ xk, const float* __restrict__ xv,
    const float* __restrict__ Wq, const float* __restrict__ Wk, const float* __restrict__ Wv,
    short* __restrict__ qb, short* __restrict__ kb, short* __restrict__ vb)
{
  __shared__ __align__(16) short wlds[96][104];
  __shared__ __align__(16) short xlds[64][104];
  const int t = threadIdx.x;
  const int p = blockIdx.x >> 9;               // 0..2
  const int blkrow0 = (blockIdx.x & 511) * 64;

  const float* x = (p == 0) ? xq : (p == 1) ? xk : xv;
  const float* W = (p == 0) ? Wq : (p == 1) ? Wk : Wv;
  short* dst = (p == 0) ? qb : (p == 1) ? kb : vb;
  const float sc = (p == 1) ? C1 : 1.0f;

  // W stage: 2304 float4 tasks / 256 thr = 9 per thread; 96%4==0 -> no straddle
#pragma unroll
  for (int i = 0; i < 9; ++i) {
    const int idx = i*256 + t;
    const float4 wv = *(const float4*)(W + (size_t)idx*4);
    const int f = idx*4, row = f/96, col = f%96;
    sh4 w4;
    w4[0] = bf16_of(wv.x); w4[1] = bf16_of(wv.y);
    w4[2] = bf16_of(wv.z); w4[3] = bf16_of(wv.w);
    *(sh4*)&wlds[row][col] = w4;
  }
#pragma unroll
  for (int it = 0; it < 3; ++it) {
    const int f = it*2048 + t*8;               // 96%8==0: no row straddle
    const int row = f / 96, col = f % 96;
    *(short8*)&xlds[row][col] = load_cvt8(x + (size_t)(blkrow0 + row)*ND + col);
  }
  __syncthreads();

  const int wave = t >> 6, lane = t & 63;
  const int g = lane >> 4, li = lane & 15;
  const int acol = g * 8;

  const short8 a0 = *(const short8*)&xlds[wave*16 + li][acol];
  const short8 a1 = *(const short8*)&xlds[wave*16 + li][32 + acol];
  const short8 a2 = *(const short8*)&xlds[wave*16 + li][64 + acol];

  f32x4 oacc[6];
#pragma unroll
  for (int tt = 0; tt < 6; ++tt) {
    f32x4 acc = {0.f, 0.f, 0.f, 0.f};
    const short* wr = &wlds[tt*16 + li][acol];
    acc = __builtin_amdgcn_mfma_f32_16x16x32_bf16(a0, *(const short8*)(wr),      acc, 0, 0, 0);
    acc = __builtin_amdgcn_mfma_f32_16x16x32_bf16(a1, *(const short8*)(wr + 32), acc, 0, 0, 0);
    acc = __builtin_amdgcn_mfma_f32_16x16x32_bf16(a2, *(const short8*)(wr + 64), acc, 0, 0, 0);
    oacc[tt] = acc;
  }

#pragma unroll
  for (int tt = 0; tt < 6; ++tt)
#pragma unroll
    for (int r = 0; r < 4; ++r)
      xlds[wave*16 + g*4 + r][tt*16 + li] = bf16_of(oacc[tt][r] * sc);
  __syncthreads();

#pragma unroll
  for (int it = 0; it < 3; ++it) {
    const int task = it*256 + t;               // 0..767 = 64 rows x 12 short8
    const int nn_l = task / 12, seg = task - nn_l*12;
    const int col8 = seg*8;
    const int h = col8 >> 5, dd = col8 & 31;
    const int n = blkrow0 + nn_l;
    const int bcx = n >> 10, nnx = n & 1023;
    *(short8*)&dst[((size_t)(bcx*NHH + h)*NN + nnx)*DKV + dd] =
        *(const short8*)&xlds[nn_l][col8];
  }
}

// ---------------------------------------------------------------------------
// Kernel 2: column softmax sums + V' = diag(1/sum)*V transposed.
// Wave owns 32 k-rows (dual A-frags); Q chunks of 128 rows staged via
// global_load_lds width=16 with IDENTITY mapping (chunk = contiguous 8KB of
// qb; linear [128][32] LDS, conflict-free B-frag reads). V' rows prefetched
// at entry. grid 96*8, block 256.
// ---------------------------------------------------------------------------
__global__ __launch_bounds__(256) void stats_kernel(
    const short* __restrict__ qb, const short* __restrict__ kb,
    const short* __restrict__ vb, short* __restrict__ vtb)
{
  __shared__ __align__(16) short s_q[2][4096];   // 2 x 8KB linear
  __shared__ float s_is[128];
  __shared__ __align__(16) short s_t[32][128];   // V' transpose buf (swizzled)

  const int t = threadIdx.x, wave = t >> 6, lane = t & 63;
  const int g = lane >> 4, li = lane & 15;
  const int head = blockIdx.x % NHEAD;           // XCD-aware
  const int kblk = blockIdx.x / NHEAD;           // 0..7
  const int kb0 = kblk*128;
  const int k0 = kb0 + wave*32;

  const short* kr = kb + ((size_t)head*NN + k0)*DKV + g*8;
  const short8 af0 = *(const short8*)(kr + (size_t)li*DKV);
  const short8 af1 = *(const short8*)(kr + (size_t)(16 + li)*DKV);

  // V'-tail prefetch (consumed in phase A after the sum loop)
  const int nl = t >> 1;              // 0..127 (local k)
  const int dvs = (t & 1) * 16;       // dv segment base
  const short* vrow = vb + ((size_t)head*NN + kb0 + nl)*DKV + dvs;
  const short8 v0 = *(const short8*)(vrow);
  const short8 v1 = *(const short8*)(vrow + 8);

  const char* qsrc = (const char*)(qb + (size_t)head*NN*DKV);
  char* sq0 = (char*)&s_q[0][0];
  char* sq1 = (char*)&s_q[1][0];
  const int wseg = wave*2048;

  f32x4 s0 = {0.f,0.f,0.f,0.f}, s1 = {0.f,0.f,0.f,0.f};

  // prologue: chunk 0 -> buf 0 (8KB = 4 waves x 2 x 1KB issues)
#pragma unroll
  for (int j = 0; j < 2; ++j)
    gload_lds16(qsrc + wseg + j*1024 + lane*16, sq0 + wseg + j*1024);
  __syncthreads();

  for (int qc = 0; qc < 8; ++qc) {
    const int cur = qc & 1;
    const short* scur = (const short*)(cur ? sq1 : sq0);
    char* snxt = cur ? sq0 : sq1;
    if (qc < 7) {
#pragma unroll
      for (int j = 0; j < 2; ++j)
        gload_lds16(qsrc + (size_t)(qc+1)*8192 + wseg + j*1024 + lane*16,
                    snxt + wseg + j*1024);
    }
    __builtin_amdgcn_s_setprio(1);
#pragma unroll
    for (int qt = 0; qt < 8; ++qt) {
      const short8 bf = *(const short8*)(scur + (qt*16 + li)*32 + g*8);
      f32x4 z = {0.f,0.f,0.f,0.f};
      f32x4 d0 = __builtin_amdgcn_mfma_f32_16x16x32_bf16(af0, bf, z, 0, 0, 0);
      f32x4 d1 = __builtin_amdgcn_mfma_f32_16x16x32_bf16(af1, bf, z, 0, 0, 0);
#pragma unroll
      for (int r = 0; r < 4; ++r) {
        s0[r] += __builtin_amdgcn_exp2f(d0[r]);
        s1[r] += __builtin_amdgcn_exp2f(d1[r]);
      }
    }
    __builtin_amdgcn_s_setprio(0);
    __syncthreads();   // drains glds (next buf ready) + orders buf reuse
  }

#pragma unroll
  for (int ms = 1; ms <= 8; ms <<= 1) {
#pragma unroll
    for (int r = 0; r < 4; ++r) {
      s0[r] += __shfl_xor(s0[r], ms);
      s1[r] += __shfl_xor(s1[r], ms);
    }
  }
  if (li == 0) {
    float* dst = s_is + wave*32 + g*4;
#pragma unroll
    for (int r = 0; r < 4; ++r) {
      dst[r]      = 1.0f / s0[r];
      dst[16 + r] = 1.0f / s1[r];
    }
  }
  __syncthreads();

  // ---- V' phase A: scale prefetched vb rows by is[n], scatter to transpose
  {
    const float isv = s_is[nl];
    short* st = &s_t[0][0];
#pragma unroll
    for (int j = 0; j < 8; ++j) {
      const int dv0 = dvs + j, dv1 = dvs + 8 + j;
      st[dv0*128 + (((nl*2) ^ ((dv0 & 7) << 4)) >> 1)] = bf16_of(isv * f_of_bf16(v0[j]));
      st[dv1*128 + (((nl*2) ^ ((dv1 & 7) << 4)) >> 1)] = bf16_of(isv * f_of_bf16(v1[j]));
    }
  }
  __syncthreads();

  // ---- V' phase B: coalesced write to vtb [head][dv][n]
  {
    const short* st = &s_t[0][0];
#pragma unroll
    for (int it = 0; it < 2; ++it) {
      const int task = it*256 + t;      // 0..511
      const int dv = task >> 4, ns = task & 15;
      short8 v = *(const short8*)(st + dv*128 + (((ns*16) ^ ((dv & 7) << 4)) >> 1));
      *(short8*)(vtb + ((size_t)head*DKV + dv)*NN + kb0 + ns*8) = v;
    }
  }
}

// ---------------------------------------------------------------------------
// Kernel 3: FUSED context + fc + LN, HEAD-PARALLEL. (round-19 body — the
// proven best: 2-buffer gload_lds staging with LINEAR LDS dest + INVERSE-
// SWIZZLED global source; swizzled reads; setprio around the MFMA cluster;
// fused fc+LN epilogue with Wfc reg-staged at entry. Round-20's 3-deep
// counted-vmcnt pipeline regressed — T4 requires 8-phase role-split, null
// on this 2-barrier structure.) grid 32*16 = 512, block 384.
// ---------------------------------------------------------------------------
__global__ __launch_bounds__(384) void ctxout_kernel(
    const short* __restrict__ qb, const short* __restrict__ kb,
    const short* __restrict__ vtb, const float* __restrict__ resid,
    const float* __restrict__ Wfc, const float* __restrict__ gamma,
    const float* __restrict__ beta, float* __restrict__ out)
{
  __shared__ __align__(16) char smem[49152];

  const int t = threadIdx.x;
  const int w = t >> 6, lane = t & 63;
  const int li = lane & 31, hi = lane >> 5;
  const int hs = t >> 7;                 // 0..2 head slot (128 thr each)
  const int sub = w & 1;                 // wave parity within slot
  const int bc = blockIdx.x % NBC;       // XCD-affine (32 % 8 == 0)
  const int qtile = blockIdx.x / NBC;    // 0..15
  const int q0 = qtile*64 + sub*32;
  const int head = bc*NHH + hs;

  // Wfc reg-stage: 9216 f32 = 384 thr x 6 float4 (coalesced).
  float4 wreg[6];
#pragma unroll
  for (int i = 0; i < 6; ++i)
    wreg[i] = *(const float4*)(Wfc + i*1536 + t*4);

  char* kbase = smem + hs*16384;         // [2][32 rows][128B] swizzled
  char* vbase = kbase + 8192;            // [2][32 rows][128B] swizzled

  const short* kgp = kb  + (size_t)head*NN*DKV;
  const short* vgp = vtb + (size_t)head*DKV*NN;
  const short* qrow = qb + ((size_t)head*NN + q0 + li)*DKV;
  const short8 qf0 = *(const short8*)(qrow + hi*8);
  const short8 qf1 = *(const short8*)(qrow + 16 + hi*8);

  // per-lane inverse-swizzled source offsets (bytes) + wave-uniform LDS segs
  int kgoff[2], vgoff[2], ldsseg[2];
#pragma unroll
  for (int j = 0; j < 2; ++j) {
    const int b = (sub*2 + j)*1024 + lane*16;   // LDS byte this lane fills
    const int r = b >> 7, c = b & 127;
    const int pc = c ^ ((r & 7) << 4);
    const int xk6 = r + 32*(pc >> 6);
    const int kr = (xk6 & 51) | ((xk6 & 4) << 1) | ((xk6 & 8) >> 1);  // tau
    kgoff[j] = kr*64 + (pc & 63);               // within 4096B K chunk
    vgoff[j] = r*(NN*2) + pc;                   // V' rows stride NN*2 bytes
    ldsseg[j] = (sub*2 + j)*1024;               // uniform per wave
  }

  int rd_off[2][2];
#pragma unroll
  for (int kt = 0; kt < 2; ++kt) {
    const int base = kt*64 + hi*16;
    rd_off[kt][0] = li*128 + ((base)      ^ ((li & 7) << 4));
    rd_off[kt][1] = li*128 + ((base + 32) ^ ((li & 7) << 4));
  }

  f32x16 acc = {0.f,0.f,0.f,0.f,0.f,0.f,0.f,0.f,0.f,0.f,0.f,0.f,0.f,0.f,0.f,0.f};

  // prologue: chunk 0 -> buf 0
#pragma unroll
  for (int j = 0; j < 2; ++j) {
    gload_lds16((const char*)kgp + kgoff[j], kbase + ldsseg[j]);
    gload_lds16((const char*)vgp + vgoff[j], vbase + ldsseg[j]);
  }
  __syncthreads();

  for (int kc = 0; kc < 16; ++kc) {
    const int cur = kc & 1;
    if (kc < 15) {
      const size_t kadv = (size_t)(kc+1)*4096;
      const int vadv = (kc+1)*128;
#pragma unroll
      for (int j = 0; j < 2; ++j) {
        gload_lds16((const char*)kgp + kadv + kgoff[j],
                    kbase + (cur^1)*4096 + ldsseg[j]);
        gload_lds16((const char*)vgp + vadv + vgoff[j],
                    vbase + (cur^1)*4096 + ldsseg[j]);
      }
    }
    const char* kc_b = kbase + cur*4096;
    const char* vc_b = vbase + cur*4096;

    __builtin_amdgcn_s_setprio(1);
#pragma unroll
    for (int kt = 0; kt < 2; ++kt) {
      const short8 a0 = *(const short8*)(kc_b + rd_off[kt][0]);
      const short8 a1 = *(const short8*)(kc_b + rd_off[kt][1]);
      f32x16 sT = {0.f,0.f,0.f,0.f,0.f,0.f,0.f,0.f,0.f,0.f,0.f,0.f,0.f,0.f,0.f,0.f};
      sT = __builtin_amdgcn_mfma_f32_32x32x16_bf16(a0, qf0, sT, 0, 0, 0);
      sT = __builtin_amdgcn_mfma_f32_32x32x16_bf16(a1, qf1, sT, 0, 0, 0);
      short8 pa0, pa1;
#pragma unroll
      for (int j = 0; j < 8; ++j) {
        pa0[j] = bf16_of(__builtin_amdgcn_exp2f(sT[j]));
        pa1[j] = bf16_of(__builtin_amdgcn_exp2f(sT[8 + j]));
      }
      const short8 vfa = *(const short8*)(vc_b + rd_off[kt][0]);
      const short8 vfb = *(const short8*)(vc_b + rd_off[kt][1]);
      acc = __builtin_amdgcn_mfma_f32_32x32x16_bf16(pa0, vfa, acc, 0, 0, 0);
      acc = __builtin_amdgcn_mfma_f32_32x32x16_bf16(pa1, vfb, acc, 0, 0, 0);
    }
    __builtin_amdgcn_s_setprio(0);

    __syncthreads();   // drains vmcnt (glds complete) + orders buf reuse
  }

  // ---- epilogue (union reuse safe: all waves past the final barrier) ----
  short* s_ct = (short*)smem;            // [64][104]
  short* wlds = (short*)(smem + 13312);  // [96][104]

#pragma unroll
  for (int reg = 0; reg < 16; ++reg) {
    const int ql = sub*32 + (reg & 3) + 8*(reg >> 2) + 4*hi;
    s_ct[ql*104 + hs*32 + li] = bf16_of(acc[reg]);
  }
  // Wfc: regs -> LDS (f = i*1536 + t*4; 96%4==0 so a float4 never straddles)
#pragma unroll
  for (int i = 0; i < 6; ++i) {
    const int f = i*1536 + t*4;
    const int row = f / 96, col = f % 96;
    sh4 w4;
    w4[0] = bf16_of(wreg[i].x); w4[1] = bf16_of(wreg[i].y);
    w4[2] = bf16_of(wreg[i].z); w4[3] = bf16_of(wreg[i].w);
    *(sh4*)&wlds[row*104 + col] = w4;
  }
  __syncthreads();

  if (w < 4) {
    const int g16 = lane >> 4, li16 = lane & 15;
    const int rbase = w*16;
    const size_t rowg = (size_t)bc*NN + qtile*64 + rbase;

    const short* ar = s_ct + (rbase + li16)*104 + g16*8;
    const short8 a0 = *(const short8*)(ar);
    const short8 a1 = *(const short8*)(ar + 32);
    const short8 a2 = *(const short8*)(ar + 64);

    float o[6][4];
#pragma unroll
    for (int tt = 0; tt < 6; ++tt) {
      f32x4 oa = {0.f, 0.f, 0.f, 0.f};
      const short* wr = wlds + (tt*16 + li16)*104 + g16*8;
      oa = __builtin_amdgcn_mfma_f32_16x16x32_bf16(a0, *(const short8*)(wr),      oa, 0, 0, 0);
      oa = __builtin_amdgcn_mfma_f32_16x16x32_bf16(a1, *(const short8*)(wr + 32), oa, 0, 0, 0);
      oa = __builtin_amdgcn_mfma_f32_16x16x32_bf16(a2, *(const short8*)(wr + 64), oa, 0, 0, 0);
#pragma unroll
      for (int r = 0; r < 4; ++r)
        o[tt][r] = oa[r] + resid[(rowg + g16*4 + r)*ND + tt*16 + li16];
    }

    float s1v[4], s2v[4];
#pragma unroll
    for (int r = 0; r < 4; ++r) {
      float a = 0.f, b = 0.f;
#pragma unroll
      for (int tt = 0; tt < 6; ++tt) { a += o[tt][r]; b += o[tt][r]*o[tt][r]; }
      s1v[r] = a; s2v[r] = b;
    }
#pragma unroll
    for (int ms = 1; ms <= 8; ms <<= 1) {
#pragma unroll
      for (int r = 0; r < 4; ++r) {
        s1v[r] += __shfl_xor(s1v[r], ms);
        s2v[r] += __shfl_xor(s2v[r], ms);
      }
    }
    float mean[4], rs[4];
#pragma unroll
    for (int r = 0; r < 4; ++r) {
      mean[r] = s1v[r] * (1.0f/96.0f);
      float var = s2v[r]*(1.0f/96.0f) - mean[r]*mean[r];
      rs[r] = rsqrtf(var + EPSV);
    }
#pragma unroll
    for (int tt = 0; tt < 6; ++tt) {
      const int e = tt*16 + li16;
      const float gg = gamma[e], bb = beta[e];
#pragma unroll
      for (int r = 0; r < 4; ++r)
        out[(rowg + g16*4 + r)*ND + e] = (o[tt][r] - mean[r])*rs[r]*gg + bb;
    }
  }
}

// ---------------------------------------------------------------------------
extern "C" void kernel_launch(void* const* d_in, const int* in_sizes, int n_in,
                              void* d_out, int out_size, void* d_ws, size_t ws_size,
                              hipStream_t stream) {
  (void)in_sizes; (void)n_in; (void)out_size; (void)ws_size;
  const float* xq    = (const float*)d_in[0];
  const float* xk    = (const float*)d_in[1];
  const float* xv    = (const float*)d_in[2];
  const float* Wq    = (const float*)d_in[3];
  const float* Wk    = (const float*)d_in[4];
  const float* Wv    = (const float*)d_in[5];
  const float* Wfc   = (const float*)d_in[6];
  const float* gamma = (const float*)d_in[7];
  const float* beta  = (const float*)d_in[8];
  float* out = (float*)d_out;

  // Workspace (18.9 MB: qb + kb + vtb + vb)
  short* qb  = (short*)d_ws;                         // [head][n][32]
  short* kb  = qb  + (size_t)NHEAD*NN*DKV;           // [head][n][32] (x C1)
  short* vtb = kb  + (size_t)NHEAD*NN*DKV;           // [head][32][n] = is[k]*V
  short* vb  = vtb + (size_t)NHEAD*NN*DKV;           // [head][n][32] (dead after stats)

  hipLaunchKernelGGL(proj_kernel,   dim3(3*NROWS/64), dim3(256), 0, stream,
                     xq, xk, xv, Wq, Wk, Wv, qb, kb, vb);
  hipLaunchKernelGGL(stats_kernel,  dim3(NHEAD*8), dim3(256), 0, stream,
                     qb, kb, vb, vtb);
  hipLaunchKernelGGL(ctxout_kernel, dim3(NBC*16), dim3(384), 0, stream,
                     qb, kb, vtb, xq, Wfc, gamma, beta, out);
}